// Round 13
// baseline (357.333 us; speedup 1.0000x reference)
//
#include <hip/hip_runtime.h>

#define NN 5000
#define FF 8
#define TT 12
#define EE 160000
#define HH 64
#define EN (EE + NN)
#define CAP (EN + 7 * NN + 64)   // padded edge capacity + prefetch slack
#define XBSTRIDE 1920000         // bytes per batch slab of x (N*F*T*4)
#define BSOFF    15360000        // 8 slabs = byte offset from batch b to b+8
#define NGRP     1250            // node groups of 4 per batch-pair queue

typedef float f2  __attribute__((ext_vector_type(2)));
typedef float f4v __attribute__((ext_vector_type(4)));

#define LOG2E 1.44269504088896340736f

// ---------------- CSR build ----------------

__global__ void k_count(const int* __restrict__ dst, int* __restrict__ deg) {
    int i = blockIdx.x * blockDim.x + threadIdx.x;
    if (i < EE) atomicAdd(&deg[dst[i]], 1);
}

// block 0: CSR offsets (padded to 8) + dinv + zero pad entries; block 1: weights
__global__ __launch_bounds__(1024) void k_scan_prep(
    const int* __restrict__ deg, int* __restrict__ offs, int* __restrict__ cursor,
    float* __restrict__ dinv, int2* __restrict__ cedge,
    const float* __restrict__ Wz, const float* __restrict__ bz,
    const float* __restrict__ Lz, const float* __restrict__ lbz,
    const float* __restrict__ Wh, const float* __restrict__ bh,
    const float* __restrict__ Lh, const float* __restrict__ lbh,
    const float* __restrict__ att, const float* __restrict__ fcW,
    float* __restrict__ G, float* __restrict__ C, float* __restrict__ sm,
    float* __restrict__ fcwT) {
    int tid = threadIdx.x;
    if (blockIdx.x == 0) {
        __shared__ int s[1024];
        int base = tid * 5;
        int pad[5], real[5];
        int part = 0;
#pragma unroll
        for (int j = 0; j < 5; ++j) {
            int n = base + j;
            int c = (n < NN) ? deg[n] + 1 : 0;   // +1 self loop
            real[j] = c;
            pad[j] = (c + 7) & ~7;               // pad to multiple of 8 entries
            part += pad[j];
        }
        s[tid] = part;
        __syncthreads();
        for (int d = 1; d < 1024; d <<= 1) {
            int v = (tid >= d) ? s[tid - d] : 0;
            __syncthreads();
            s[tid] += v;
            __syncthreads();
        }
        int run = s[tid] - part;  // exclusive prefix
#pragma unroll
        for (int j = 0; j < 5; ++j) {
            int n = base + j;
            if (n < NN) {
                offs[n] = run;
                cursor[n] = run;
                dinv[n] = rsqrtf((float)real[j]);
                for (int e = real[j]; e < pad[j]; ++e)   // zero pad entries only
                    cedge[run + e] = make_int2(0, 0);
                run += pad[j];
            }
        }
        if (tid == 1023) {
            offs[NN] = s[1023];
            for (int k = 0; k < 64; ++k)                 // zero prefetch slack
                cedge[s[1023] + k] = make_int2(0, 0);
        }
    } else {
        // G = W @ L[:64] (two gates), C = b @ L[:64] + lb; pre-scaled by log2e
        // (z gate) and 2*log2e (h gate) so the dense phase uses raw exp2.
        if (tid < 1024) {
            int g = tid >> 9, rem = tid & 511, f = rem >> 6, o = rem & 63;
            const float* W = g ? Wh : Wz;
            const float* L = g ? Lh : Lz;
            float acc = 0.f;
            for (int k = 0; k < 64; ++k) acc += W[f * 64 + k] * L[k * 64 + o];
            G[tid] = acc * (g ? 2.0f * LOG2E : LOG2E);
        }
        if (tid < 128) {
            int g = tid >> 6, o = tid & 63;
            const float* b = g ? bh : bz;
            const float* L = g ? Lh : Lz;
            const float* lb = g ? lbh : lbz;
            float acc = lb[o];
            for (int k = 0; k < 64; ++k) acc += b[k] * L[k * 64 + o];
            C[tid] = acc * (g ? 2.0f * LOG2E : LOG2E);
        }
        if (tid < 768) {
            int t = tid >> 6, o = tid & 63;
            fcwT[tid] = fcW[o * TT + t];     // transposed fc weights [t][h]
        }
        if (tid == 0) {
            float m = att[0];
            for (int t = 1; t < TT; ++t) m = fmaxf(m, att[t]);
            float e[TT], ss = 0.f;
            for (int t = 0; t < TT; ++t) { e[t] = __expf(att[t] - m); ss += e[t]; }
            for (int t = 0; t < TT; ++t) sm[t] = e[t] / ss;
        }
    }
}

__global__ void k_fill(const int* __restrict__ src, const int* __restrict__ dst,
                       int* cursor, const float* __restrict__ dinv,
                       int2* __restrict__ cedge) {
    int i = blockIdx.x * blockDim.x + threadIdx.x;
    if (i < EE) {
        int s = src[i], d = dst[i];
        int p = atomicAdd(&cursor[d], 1);
        cedge[p] = make_int2(s, __float_as_int(dinv[s] * dinv[d]));
    } else if (i < EN) {
        int n = i - EE;
        int p = atomicAdd(&cursor[n], 1);
        cedge[p] = make_int2(n, __float_as_int(dinv[n] * dinv[n]));
    }
}

// ---------------- persistent fused kernel with XCD-keyed work queues -------
// 8 queues, one per batch-pair bp (slabs {bp, bp+8} = 3.84 MB, L2-resident).
// Each block reads HW_REG_XCC_ID and drains ITS XCD's queue first (L2
// locality independent of the blockIdx->XCD mapping), then steals from the
// other queues -> correctness independent of scheduling (each group claimed
// exactly once via atomicAdd). Weights staged in LDS once per block.

#define E2C(Q)                                                    \
    {                                                             \
        unsigned a0_ = (unsigned)(Q).x * 384u + voff;             \
        unsigned a1_ = (unsigned)(Q).z * 384u + voff;             \
        f4v v0_ = *(const f4v*)(xbb + a0_);                       \
        f4v v1_ = *(const f4v*)(xbb + a1_);                       \
        acc0 += __int_as_float((Q).y) * v0_;                      \
        acc1 += __int_as_float((Q).w) * v1_;                      \
    }

__global__ __launch_bounds__(256) void k_node(
    const float* __restrict__ x, const int* __restrict__ offs,
    const int2* __restrict__ cedge,
    const float* __restrict__ G, const float* __restrict__ C,
    const float* __restrict__ sm, const float* __restrict__ fcwT,
    const float* __restrict__ fcb, int* __restrict__ qctr,
    float* __restrict__ out) {
    __shared__ __align__(16) float Glds[1024];
    __shared__ __align__(16) float Clds[128];
    __shared__ __align__(16) float fcw[768];   // [t][h] layout (fcwT)
    __shared__ __align__(16) float sml[16];
    __shared__ __align__(16) float xals[4][2][96];
    __shared__ __align__(16) float hl[4][2][64];
    __shared__ int gsh;

    const int tid = threadIdx.x;
    const int wid = tid >> 6;
    const int lane = tid & 63;

    // stage weights once per block
    ((f4v*)Glds)[tid] = ((const f4v*)G)[tid];
    if (tid < 192) ((f4v*)fcw)[tid] = ((const f4v*)fcwT)[tid];
    if (tid < 32) ((f4v*)Clds)[tid] = ((const f4v*)C)[tid];
    if (tid < 12) sml[tid] = sm[tid];
    __syncthreads();

    float gz[FF], gh[FF];
#pragma unroll
    for (int f = 0; f < FF; ++f) {
        gz[f] = Glds[f * 64 + lane];
        gh[f] = Glds[512 + f * 64 + lane];
    }
    const float cz = Clds[lane], ch = Clds[64 + lane];
    float smv[TT];
#pragma unroll
    for (int t = 0; t < TT; ++t) smv[t] = sml[t];

    int myx;
    asm volatile("s_getreg_b32 %0, hwreg(HW_REG_XCC_ID)" : "=s"(myx));
    myx &= 7;

    for (int p = 0; p < 8; ++p) {
        const int bp = (myx + p) & 7;          // own queue first, then steal
        const char* xbb = (const char*)x + (size_t)bp * XBSTRIDE;
        for (;;) {
            if (tid == 0) gsh = atomicAdd(&qctr[bp], 1);
            __syncthreads();
            const int grp = gsh;
            __syncthreads();
            if (grp >= NGRP) break;

            const int n = grp * 4 + wid;
            int r0 = __builtin_amdgcn_readfirstlane(offs[n]);
            int r1 = __builtin_amdgcn_readfirstlane(offs[n + 1]);

            if (lane < 48) {
                const unsigned voff =
                    (unsigned)(lane / 24) * BSOFF + (unsigned)(lane % 24) * 16u;
                f4v acc0 = {0.f, 0.f, 0.f, 0.f};
                f4v acc1 = {0.f, 0.f, 0.f, 0.f};
                const int4* ce = (const int4*)cedge;   // 2 edges per int4
                int c = r0 >> 1;
                const int c1 = r1 >> 1;
                int4 A0 = ce[c], A1 = ce[c + 1], A2 = ce[c + 2], A3 = ce[c + 3];
                int4 B0 = ce[c + 4], B1 = ce[c + 5], B2 = ce[c + 6], B3 = ce[c + 7];
                while (true) {
                    int4 D0 = A0, D1 = A1, D2 = A2, D3 = A3;
                    A0 = B0; A1 = B1; A2 = B2; A3 = B3;
                    B0 = ce[c + 8]; B1 = ce[c + 9];
                    B2 = ce[c + 10]; B3 = ce[c + 11];
                    E2C(D0) E2C(D1) E2C(D2) E2C(D3)
                    c += 4;
                    if (c >= c1) break;
                }
                f4v acc = acc0 + acc1;
                *(f4v*)&xals[wid][lane / 24][(lane % 24) * 4] = acc;
            }
            // xals is wave-private: no barrier needed before the dense phase.

#pragma unroll
            for (int bs = 0; bs < 2; ++bs) {
                float hacc0 = 0.f, hacc1 = 0.f;
#pragma unroll
                for (int tq = 0; tq < 3; ++tq) {
                    f4v xq[FF];
#pragma unroll
                    for (int f = 0; f < FF; ++f)
                        xq[f] = *(const f4v*)&xals[wid][bs][f * TT + tq * 4];
#pragma unroll
                    for (int half = 0; half < 2; ++half) {
                        f2 az = {cz, cz}, ah = {ch, ch};
#pragma unroll
                        for (int f = 0; f < FF; ++f) {
                            f2 v = half ? xq[f].hi : xq[f].lo;
                            az += v * gz[f];
                            ah += v * gh[f];
                        }
                        {
                            float ea = exp2f(az[0]);
                            float e2h = exp2f(ah[0]);
                            float num = e2h - 1.0f;
                            float den = (1.0f + ea) * (1.0f + e2h);
                            hacc0 += smv[tq * 4 + half * 2] * num *
                                     __builtin_amdgcn_rcpf(den);
                        }
                        {
                            float ea = exp2f(az[1]);
                            float e2h = exp2f(ah[1]);
                            float num = e2h - 1.0f;
                            float den = (1.0f + ea) * (1.0f + e2h);
                            hacc1 += smv[tq * 4 + half * 2 + 1] * num *
                                     __builtin_amdgcn_rcpf(den);
                        }
                    }
                }
                hl[wid][bs][lane] = hacc0 + hacc1;
            }
            __syncthreads();   // hl complete across the 4 waves

            // fc: 4 nodes x 2 bs x 12 t = 96 outputs; fcw is [t][h] (fcwT)
            if (tid < 96) {
                int nw = tid / 24;
                int rem = tid % 24;
                int bs = rem / 12;
                int t = rem % 12;
                float acc = fcb[t];
                const float* hrow = &hl[nw][bs][0];
                const float* wrow = &fcw[t * 64];
#pragma unroll
                for (int o4 = 0; o4 < 16; ++o4) {
                    f4v h4 = *(const f4v*)&hrow[o4 * 4];
                    f4v w4 = *(const f4v*)&wrow[o4 * 4];
                    acc += h4[0] * w4[0] + h4[1] * w4[1] +
                           h4[2] * w4[2] + h4[3] * w4[3];
                }
                int b = bp + bs * 8;
                int n2 = grp * 4 + nw;
                out[((size_t)b * NN + n2) * TT + t] = acc;
            }
            __syncthreads();   // protect gsh/hl reuse next iteration
        }
    }
}

extern "C" void kernel_launch(void* const* d_in, const int* in_sizes, int n_in,
                              void* d_out, int out_size, void* d_ws, size_t ws_size,
                              hipStream_t stream) {
    const float* x   = (const float*)d_in[0];
    const int*   ei  = (const int*)d_in[1];
    const float* Wz  = (const float*)d_in[2];
    const float* bz  = (const float*)d_in[3];
    const float* Lz  = (const float*)d_in[4];
    const float* lbz = (const float*)d_in[5];
    // d_in[6..9] = Wr, br, Lr, lbr : dead (H == 0)
    const float* Wh  = (const float*)d_in[10];
    const float* bh  = (const float*)d_in[11];
    const float* Lh  = (const float*)d_in[12];
    const float* lbh = (const float*)d_in[13];
    const float* att = (const float*)d_in[14];
    const float* fcW = (const float*)d_in[15];
    const float* fcb = (const float*)d_in[16];
    float* out = (float*)d_out;

    const int* src = ei;
    const int* dst = ei + EE;

    int2*  cedge  = (int2*)d_ws;             // CAP entries (pads zeroed in prep)
    int*   qctr   = (int*)(cedge + CAP);     // 16 (zeroed)
    int*   deg    = qctr + 16;               // N (zeroed)
    int*   cursor = deg + NN;                // N
    int*   offs   = cursor + NN;             // N+1
    float* dinv   = (float*)(offs + NN + 1); // N
    float* G      = dinv + NN;               // 2*8*64
    float* C      = G + 1024;                // 2*64
    float* sm     = C + 128;                 // 16
    float* fcwT   = sm + 16;                 // 768

    (void)hipMemsetAsync(qctr, 0, (16 + NN) * sizeof(int), stream);
    hipLaunchKernelGGL(k_count, dim3((EE + 255) / 256), dim3(256), 0, stream, dst, deg);
    hipLaunchKernelGGL(k_scan_prep, dim3(2), dim3(1024), 0, stream,
                       deg, offs, cursor, dinv, cedge,
                       Wz, bz, Lz, lbz, Wh, bh, Lh, lbh, att, fcW, G, C, sm, fcwT);
    hipLaunchKernelGGL(k_fill, dim3((EN + 255) / 256), dim3(256), 0, stream,
                       src, dst, cursor, dinv, cedge);
    hipLaunchKernelGGL(k_node, dim3(2048), dim3(256), 0, stream,
                       x, offs, cedge, G, C, sm, fcwT, fcb, qctr, out);
}

// Round 14
// 142.221 us; speedup vs baseline: 2.5125x; 2.5125x over previous
//
#include <hip/hip_runtime.h>

#define NN 5000
#define FF 8
#define TT 12
#define EE 160000
#define HH 64
#define EN (EE + NN)
#define CAP (EN + 7 * NN + 64)   // padded edge capacity + prefetch slack
#define XBSTRIDE 1920000         // bytes per batch slab of x (N*F*T*4)
#define BSOFF    15360000        // 8 slabs = byte offset from batch b to b+8

typedef float f2  __attribute__((ext_vector_type(2)));
typedef float f4v __attribute__((ext_vector_type(4)));

#define LOG2E 1.44269504088896340736f

// ---------------- CSR build ----------------

__global__ void k_count(const int* __restrict__ dst, int* __restrict__ deg) {
    int i = blockIdx.x * blockDim.x + threadIdx.x;
    if (i < EE) atomicAdd(&deg[dst[i]], 1);
}

// block 0: CSR offsets (padded to 8) + dinv + inline pad zeroing (1024 thr,
// 5 nodes each); block 1: weight folding + softmax
__global__ __launch_bounds__(1024) void k_scan_prep(
    const int* __restrict__ deg, int* __restrict__ offs, int* __restrict__ cursor,
    float* __restrict__ dinv, int2* __restrict__ cedge,
    const float* __restrict__ Wz, const float* __restrict__ bz,
    const float* __restrict__ Lz, const float* __restrict__ lbz,
    const float* __restrict__ Wh, const float* __restrict__ bh,
    const float* __restrict__ Lh, const float* __restrict__ lbh,
    const float* __restrict__ att,
    float* __restrict__ G, float* __restrict__ C, float* __restrict__ sm) {
    int tid = threadIdx.x;
    if (blockIdx.x == 0) {
        __shared__ int s[1024];
        int base = tid * 5;
        int pad[5], real[5];
        int part = 0;
#pragma unroll
        for (int j = 0; j < 5; ++j) {
            int n = base + j;
            int c = (n < NN) ? deg[n] + 1 : 0;   // +1 self loop
            real[j] = c;
            pad[j] = (c + 7) & ~7;               // pad to multiple of 8 entries
            part += pad[j];
        }
        s[tid] = part;
        __syncthreads();
        for (int d = 1; d < 1024; d <<= 1) {
            int v = (tid >= d) ? s[tid - d] : 0;
            __syncthreads();
            s[tid] += v;
            __syncthreads();
        }
        int run = s[tid] - part;  // exclusive prefix
#pragma unroll
        for (int j = 0; j < 5; ++j) {
            int n = base + j;
            if (n < NN) {
                offs[n] = run;
                cursor[n] = run;
                dinv[n] = rsqrtf((float)real[j]);
                for (int e = real[j]; e < pad[j]; ++e)   // zero only pad entries
                    cedge[run + e] = make_int2(0, 0);
                run += pad[j];
            }
        }
        if (tid == 1023) {
            offs[NN] = s[1023];
            for (int k = 0; k < 64; ++k)                 // zero prefetch slack
                cedge[s[1023] + k] = make_int2(0, 0);
        }
    } else {
        // G = W @ L[:64] (two gates), C = b @ L[:64] + lb; pre-scaled by log2e
        // (z gate) and 2*log2e (h gate) so the dense phase uses raw exp2.
        if (tid < 1024) {
            int g = tid >> 9, rem = tid & 511, f = rem >> 6, o = rem & 63;
            const float* W = g ? Wh : Wz;
            const float* L = g ? Lh : Lz;
            float acc = 0.f;
            for (int k = 0; k < 64; ++k) acc += W[f * 64 + k] * L[k * 64 + o];
            G[tid] = acc * (g ? 2.0f * LOG2E : LOG2E);
        }
        if (tid < 128) {
            int g = tid >> 6, o = tid & 63;
            const float* b = g ? bh : bz;
            const float* L = g ? Lh : Lz;
            const float* lb = g ? lbh : lbz;
            float acc = lb[o];
            for (int k = 0; k < 64; ++k) acc += b[k] * L[k * 64 + o];
            C[tid] = acc * (g ? 2.0f * LOG2E : LOG2E);
        }
        if (tid == 0) {
            float m = att[0];
            for (int t = 1; t < TT; ++t) m = fmaxf(m, att[t]);
            float e[TT], ss = 0.f;
            for (int t = 0; t < TT; ++t) { e[t] = __expf(att[t] - m); ss += e[t]; }
            for (int t = 0; t < TT; ++t) sm[t] = e[t] / ss;
        }
    }
}

__global__ void k_fill(const int* __restrict__ src, const int* __restrict__ dst,
                       int* cursor, const float* __restrict__ dinv,
                       int2* __restrict__ cedge) {
    int i = blockIdx.x * blockDim.x + threadIdx.x;
    if (i < EE) {
        int s = src[i], d = dst[i];
        int p = atomicAdd(&cursor[d], 1);
        cedge[p] = make_int2(s, __float_as_int(dinv[s] * dinv[d]));
    } else if (i < EN) {
        int n = i - EE;
        int p = atomicAdd(&cursor[n], 1);
        cedge[p] = make_int2(n, __float_as_int(dinv[n] * dinv[n]));
    }
    // pad entries zeroed inline by k_scan_prep: node 0, weight 0 -> no-op.
}

// ---------------- fused gather + gates + attention + fc (round-6, verbatim) --
// blockIdx % 8 = bp  -> XCD bp only touches batches {bp, bp+8}: L2-resident.
// block = 4 waves; wave = one node, 2 batches; lane<48 owns one float4.
// Edge lists padded to 8-entry multiples: no tails; wave-uniform int4 chunk
// loads (SGPR) with 2-iteration rotating prefetch.

#define E2(Q)                                                     \
    {                                                             \
        unsigned a0_ = (unsigned)(Q).x * 384u + voff;             \
        unsigned a1_ = (unsigned)(Q).z * 384u + voff;             \
        f4v v0_ = *(const f4v*)(xbb + a0_);                       \
        f4v v1_ = *(const f4v*)(xbb + a1_);                       \
        acc += __int_as_float((Q).y) * v0_;                       \
        acc += __int_as_float((Q).w) * v1_;                       \
    }

__global__ __launch_bounds__(256) void k_fused(
    const float* __restrict__ x, const int* __restrict__ offs,
    const int2* __restrict__ cedge,
    const float* __restrict__ G, const float* __restrict__ C,
    const float* __restrict__ sm, const float* __restrict__ fcW,
    const float* __restrict__ fcb, float* __restrict__ out) {
    __shared__ __align__(16) float xals[4][2][96];
    __shared__ __align__(16) float hl[4][2][72];   // 72: 16B-aligned rows, staggered banks
    __shared__ __align__(16) float fcw[768];
    __shared__ __align__(16) float Glds[1024];
    __shared__ __align__(16) float Clds[128];

    const int tid = threadIdx.x;
    const int wid = tid >> 6;
    const int lane = tid & 63;
    const int bp = blockIdx.x & 7;       // batch pair {bp, bp+8} -> XCD bp
    const int g = blockIdx.x >> 3;
    const int n = g * 4 + wid;

    // stage weights into LDS (complete before first __syncthreads)
    ((f4v*)Glds)[tid] = ((const f4v*)G)[tid];
    if (tid < 192) ((f4v*)fcw)[tid] = ((const f4v*)fcW)[tid];
    if (tid < 32) ((f4v*)Clds)[tid] = ((const f4v*)C)[tid];

    int r0 = __builtin_amdgcn_readfirstlane(offs[n]);
    int r1 = __builtin_amdgcn_readfirstlane(offs[n + 1]);

    const char* xbb = (const char*)x + (size_t)bp * XBSTRIDE;

    if (lane < 48) {
        const unsigned voff = (unsigned)(lane / 24) * BSOFF + (unsigned)(lane % 24) * 16u;
        f4v acc = {0.f, 0.f, 0.f, 0.f};

        const int4* ce = (const int4*)cedge;   // 2 edges per int4
        int c = r0 >> 1;                       // int4 index, multiple of 4
        const int c1 = r1 >> 1;
        int4 A0 = ce[c], A1 = ce[c + 1], A2 = ce[c + 2], A3 = ce[c + 3];
        int4 B0 = ce[c + 4], B1 = ce[c + 5], B2 = ce[c + 6], B3 = ce[c + 7];
        while (true) {
            int4 D0 = A0, D1 = A1, D2 = A2, D3 = A3;
            A0 = B0; A1 = B1; A2 = B2; A3 = B3;
            B0 = ce[c + 8]; B1 = ce[c + 9]; B2 = ce[c + 10]; B3 = ce[c + 11];
            E2(D0) E2(D1) E2(D2) E2(D3)
            c += 4;
            if (c >= c1) break;
        }
        *(f4v*)&xals[wid][lane / 24][(lane % 24) * 4] = acc;
    }
    __syncthreads();

    // ---- dense gates (lane = hidden channel o); packed f2 over t-pairs.
    // az,ah are pre-scaled by log2e/2log2e; (1-z)*tanh = (e2h-1)/((1+ea)(1+e2h)).
    float gz[FF], gh[FF];
#pragma unroll
    for (int f = 0; f < FF; ++f) {
        gz[f] = Glds[f * 64 + lane];
        gh[f] = Glds[512 + f * 64 + lane];
    }
    float cz = Clds[lane], ch = Clds[64 + lane];
    float smv[TT];
#pragma unroll
    for (int t = 0; t < TT; ++t) smv[t] = sm[t];

#pragma unroll
    for (int bs = 0; bs < 2; ++bs) {
        float hacc = 0.f;
#pragma unroll
        for (int tq = 0; tq < 3; ++tq) {
            f4v xq[FF];
#pragma unroll
            for (int f = 0; f < FF; ++f)
                xq[f] = *(const f4v*)&xals[wid][bs][f * TT + tq * 4];  // broadcast b128
#pragma unroll
            for (int half = 0; half < 2; ++half) {
                f2 az = {cz, cz}, ah = {ch, ch};
#pragma unroll
                for (int f = 0; f < FF; ++f) {
                    f2 v = half ? xq[f].hi : xq[f].lo;
                    az += v * gz[f];
                    ah += v * gh[f];
                }
#pragma unroll
                for (int j = 0; j < 2; ++j) {
                    float ea = exp2f(az[j]);    // v_exp_f32
                    float e2h = exp2f(ah[j]);   // v_exp_f32
                    float num = e2h - 1.0f;
                    float den = (1.0f + ea) * (1.0f + e2h);
                    hacc += smv[tq * 4 + half * 2 + j] * num * __builtin_amdgcn_rcpf(den);
                }
            }
        }
        hl[wid][bs][lane] = hacc;
    }
    __syncthreads();

    // ---- fc: 4 nodes x 2 batches x 6 t-pairs = 48 threads, packed f2
    if (tid < 48) {
        int nw = tid / 12;
        int rem = tid % 12;
        int bs = rem / 6;
        int tp = rem % 6;
        f2 acc;
        acc[0] = fcb[2 * tp];
        acc[1] = fcb[2 * tp + 1];
        const float* hrow = &hl[nw][bs][0];
#pragma unroll
        for (int o4 = 0; o4 < 16; ++o4) {
            f4v h4 = *(const f4v*)&hrow[o4 * 4];
            f2 w0 = *(const f2*)&fcw[(o4 * 4 + 0) * TT + 2 * tp];
            f2 w1 = *(const f2*)&fcw[(o4 * 4 + 1) * TT + 2 * tp];
            f2 w2 = *(const f2*)&fcw[(o4 * 4 + 2) * TT + 2 * tp];
            f2 w3 = *(const f2*)&fcw[(o4 * 4 + 3) * TT + 2 * tp];
            acc += h4[0] * w0;
            acc += h4[1] * w1;
            acc += h4[2] * w2;
            acc += h4[3] * w3;
        }
        int b = bp + bs * 8;
        int nn2 = g * 4 + nw;
        *(f2*)&out[((size_t)b * NN + nn2) * TT + 2 * tp] = acc;
    }
}

extern "C" void kernel_launch(void* const* d_in, const int* in_sizes, int n_in,
                              void* d_out, int out_size, void* d_ws, size_t ws_size,
                              hipStream_t stream) {
    const float* x   = (const float*)d_in[0];
    const int*   ei  = (const int*)d_in[1];
    const float* Wz  = (const float*)d_in[2];
    const float* bz  = (const float*)d_in[3];
    const float* Lz  = (const float*)d_in[4];
    const float* lbz = (const float*)d_in[5];
    // d_in[6..9] = Wr, br, Lr, lbr : dead (H == 0)
    const float* Wh  = (const float*)d_in[10];
    const float* bh  = (const float*)d_in[11];
    const float* Lh  = (const float*)d_in[12];
    const float* lbh = (const float*)d_in[13];
    const float* att = (const float*)d_in[14];
    const float* fcW = (const float*)d_in[15];
    const float* fcb = (const float*)d_in[16];
    float* out = (float*)d_out;

    const int* src = ei;
    const int* dst = ei + EE;

    int2*  cedge  = (int2*)d_ws;             // CAP entries (pads zeroed in prep)
    int*   deg    = (int*)(cedge + CAP);     // N (zeroed by small memset)
    int*   cursor = deg + NN;                // N
    int*   offs   = cursor + NN;             // N+1
    float* dinv   = (float*)(offs + NN + 1); // N
    float* G      = dinv + NN;               // 2*8*64
    float* C      = G + 1024;                // 2*64
    float* sm     = C + 128;                 // 16

    (void)hipMemsetAsync(deg, 0, NN * sizeof(int), stream);
    hipLaunchKernelGGL(k_count, dim3((EE + 255) / 256), dim3(256), 0, stream, dst, deg);
    hipLaunchKernelGGL(k_scan_prep, dim3(2), dim3(1024), 0, stream,
                       deg, offs, cursor, dinv, cedge,
                       Wz, bz, Lz, lbz, Wh, bh, Lh, lbh, att, G, C, sm);
    hipLaunchKernelGGL(k_fill, dim3((EN + 255) / 256), dim3(256), 0, stream,
                       src, dst, cursor, dinv, cedge);
    hipLaunchKernelGGL(k_fused, dim3(1250 * 8), dim3(256), 0, stream,
                       x, offs, cedge, G, C, sm, fcW, fcb, out);
}

// Round 15
// 133.617 us; speedup vs baseline: 2.6743x; 1.0644x over previous
//
#include <hip/hip_runtime.h>

#define NN 5000
#define FF 8
#define TT 12
#define EE 160000
#define HH 64
#define EN (EE + NN)
#define CAP (EN + 7 * NN + 64)   // padded edge capacity + prefetch slack
#define XBSTRIDE 1920000         // bytes per batch slab of x (N*F*T*4)
#define BSOFF    15360000        // 8 slabs = byte offset from batch b to b+8

typedef float f2  __attribute__((ext_vector_type(2)));
typedef float f4v __attribute__((ext_vector_type(4)));

#define LOG2E 1.44269504088896340736f

// ---------------- CSR build ----------------

__global__ void k_count(const int* __restrict__ dst, int* __restrict__ deg) {
    int i = blockIdx.x * blockDim.x + threadIdx.x;
    if (i < EE) atomicAdd(&deg[dst[i]], 1);
}

// block 0: CSR offsets (padded to 8) + dinv scan (1024 thr, 5 nodes each);
// block 1: weight folding + softmax. Pad entries zeroed by the bulk memset.
__global__ __launch_bounds__(1024) void k_scan_prep(
    const int* __restrict__ deg, int* __restrict__ offs, int* __restrict__ cursor,
    float* __restrict__ dinv,
    const float* __restrict__ Wz, const float* __restrict__ bz,
    const float* __restrict__ Lz, const float* __restrict__ lbz,
    const float* __restrict__ Wh, const float* __restrict__ bh,
    const float* __restrict__ Lh, const float* __restrict__ lbh,
    const float* __restrict__ att,
    float* __restrict__ G, float* __restrict__ C, float* __restrict__ sm) {
    int tid = threadIdx.x;
    if (blockIdx.x == 0) {
        __shared__ int s[1024];
        int base = tid * 5;
        int pad[5], real[5];
        int part = 0;
#pragma unroll
        for (int j = 0; j < 5; ++j) {
            int n = base + j;
            int c = (n < NN) ? deg[n] + 1 : 0;   // +1 self loop
            real[j] = c;
            pad[j] = (c + 7) & ~7;               // pad to multiple of 8 entries
            part += pad[j];
        }
        s[tid] = part;
        __syncthreads();
        for (int d = 1; d < 1024; d <<= 1) {
            int v = (tid >= d) ? s[tid - d] : 0;
            __syncthreads();
            s[tid] += v;
            __syncthreads();
        }
        int run = s[tid] - part;  // exclusive prefix
#pragma unroll
        for (int j = 0; j < 5; ++j) {
            int n = base + j;
            if (n < NN) {
                offs[n] = run;
                cursor[n] = run;
                dinv[n] = rsqrtf((float)real[j]);
                run += pad[j];
            }
        }
        if (tid == 1023) offs[NN] = s[1023];
    } else {
        // G = W @ L[:64] (two gates), C = b @ L[:64] + lb; pre-scaled by log2e
        // (z gate) and 2*log2e (h gate) so the dense phase uses raw exp2.
        if (tid < 1024) {
            int g = tid >> 9, rem = tid & 511, f = rem >> 6, o = rem & 63;
            const float* W = g ? Wh : Wz;
            const float* L = g ? Lh : Lz;
            float acc = 0.f;
            for (int k = 0; k < 64; ++k) acc += W[f * 64 + k] * L[k * 64 + o];
            G[tid] = acc * (g ? 2.0f * LOG2E : LOG2E);
        }
        if (tid < 128) {
            int g = tid >> 6, o = tid & 63;
            const float* b = g ? bh : bz;
            const float* L = g ? Lh : Lz;
            const float* lb = g ? lbh : lbz;
            float acc = lb[o];
            for (int k = 0; k < 64; ++k) acc += b[k] * L[k * 64 + o];
            C[tid] = acc * (g ? 2.0f * LOG2E : LOG2E);
        }
        if (tid == 0) {
            float m = att[0];
            for (int t = 1; t < TT; ++t) m = fmaxf(m, att[t]);
            float e[TT], ss = 0.f;
            for (int t = 0; t < TT; ++t) { e[t] = __expf(att[t] - m); ss += e[t]; }
            for (int t = 0; t < TT; ++t) sm[t] = e[t] / ss;
        }
    }
}

__global__ void k_fill(const int* __restrict__ src, const int* __restrict__ dst,
                       int* cursor, const float* __restrict__ dinv,
                       int2* __restrict__ cedge) {
    int i = blockIdx.x * blockDim.x + threadIdx.x;
    if (i < EE) {
        int s = src[i], d = dst[i];
        int p = atomicAdd(&cursor[d], 1);
        cedge[p] = make_int2(s, __float_as_int(dinv[s] * dinv[d]));
    } else if (i < EN) {
        int n = i - EE;
        int p = atomicAdd(&cursor[n], 1);
        cedge[p] = make_int2(n, __float_as_int(dinv[n] * dinv[n]));
    }
    // pad entries stay (0, 0.0f) from the memset: node 0, weight 0 -> no-op.
}

// ---------------- fused gather + gates + attention + fc (round-6, verbatim) --
// blockIdx % 8 = bp  -> XCD bp only touches batches {bp, bp+8}: L2-resident.
// block = 4 waves; wave = one node, 2 batches; lane<48 owns one float4.
// Edge lists padded to 8-entry multiples: no tails; wave-uniform int4 chunk
// loads (SGPR) with 2-iteration rotating prefetch.

#define E2(Q)                                                     \
    {                                                             \
        unsigned a0_ = (unsigned)(Q).x * 384u + voff;             \
        unsigned a1_ = (unsigned)(Q).z * 384u + voff;             \
        f4v v0_ = *(const f4v*)(xbb + a0_);                       \
        f4v v1_ = *(const f4v*)(xbb + a1_);                       \
        acc += __int_as_float((Q).y) * v0_;                       \
        acc += __int_as_float((Q).w) * v1_;                       \
    }

__global__ __launch_bounds__(256) void k_fused(
    const float* __restrict__ x, const int* __restrict__ offs,
    const int2* __restrict__ cedge,
    const float* __restrict__ G, const float* __restrict__ C,
    const float* __restrict__ sm, const float* __restrict__ fcW,
    const float* __restrict__ fcb, float* __restrict__ out) {
    __shared__ __align__(16) float xals[4][2][96];
    __shared__ __align__(16) float hl[4][2][72];   // 72: 16B-aligned rows, staggered banks
    __shared__ __align__(16) float fcw[768];
    __shared__ __align__(16) float Glds[1024];
    __shared__ __align__(16) float Clds[128];

    const int tid = threadIdx.x;
    const int wid = tid >> 6;
    const int lane = tid & 63;
    const int bp = blockIdx.x & 7;       // batch pair {bp, bp+8} -> XCD bp
    const int g = blockIdx.x >> 3;
    const int n = g * 4 + wid;

    // stage weights into LDS (complete before first __syncthreads)
    ((f4v*)Glds)[tid] = ((const f4v*)G)[tid];
    if (tid < 192) ((f4v*)fcw)[tid] = ((const f4v*)fcW)[tid];
    if (tid < 32) ((f4v*)Clds)[tid] = ((const f4v*)C)[tid];

    int r0 = __builtin_amdgcn_readfirstlane(offs[n]);
    int r1 = __builtin_amdgcn_readfirstlane(offs[n + 1]);

    const char* xbb = (const char*)x + (size_t)bp * XBSTRIDE;

    if (lane < 48) {
        const unsigned voff = (unsigned)(lane / 24) * BSOFF + (unsigned)(lane % 24) * 16u;
        f4v acc = {0.f, 0.f, 0.f, 0.f};

        const int4* ce = (const int4*)cedge;   // 2 edges per int4
        int c = r0 >> 1;                       // int4 index, multiple of 4
        const int c1 = r1 >> 1;
        int4 A0 = ce[c], A1 = ce[c + 1], A2 = ce[c + 2], A3 = ce[c + 3];
        int4 B0 = ce[c + 4], B1 = ce[c + 5], B2 = ce[c + 6], B3 = ce[c + 7];
        while (true) {
            int4 D0 = A0, D1 = A1, D2 = A2, D3 = A3;
            A0 = B0; A1 = B1; A2 = B2; A3 = B3;
            B0 = ce[c + 8]; B1 = ce[c + 9]; B2 = ce[c + 10]; B3 = ce[c + 11];
            E2(D0) E2(D1) E2(D2) E2(D3)
            c += 4;
            if (c >= c1) break;
        }
        *(f4v*)&xals[wid][lane / 24][(lane % 24) * 4] = acc;
    }
    __syncthreads();

    // ---- dense gates (lane = hidden channel o); packed f2 over t-pairs.
    // az,ah are pre-scaled by log2e/2log2e; (1-z)*tanh = (e2h-1)/((1+ea)(1+e2h)).
    float gz[FF], gh[FF];
#pragma unroll
    for (int f = 0; f < FF; ++f) {
        gz[f] = Glds[f * 64 + lane];
        gh[f] = Glds[512 + f * 64 + lane];
    }
    float cz = Clds[lane], ch = Clds[64 + lane];
    float smv[TT];
#pragma unroll
    for (int t = 0; t < TT; ++t) smv[t] = sm[t];

#pragma unroll
    for (int bs = 0; bs < 2; ++bs) {
        float hacc = 0.f;
#pragma unroll
        for (int tq = 0; tq < 3; ++tq) {
            f4v xq[FF];
#pragma unroll
            for (int f = 0; f < FF; ++f)
                xq[f] = *(const f4v*)&xals[wid][bs][f * TT + tq * 4];  // broadcast b128
#pragma unroll
            for (int half = 0; half < 2; ++half) {
                f2 az = {cz, cz}, ah = {ch, ch};
#pragma unroll
                for (int f = 0; f < FF; ++f) {
                    f2 v = half ? xq[f].hi : xq[f].lo;
                    az += v * gz[f];
                    ah += v * gh[f];
                }
#pragma unroll
                for (int j = 0; j < 2; ++j) {
                    float ea = exp2f(az[j]);    // v_exp_f32
                    float e2h = exp2f(ah[j]);   // v_exp_f32
                    float num = e2h - 1.0f;
                    float den = (1.0f + ea) * (1.0f + e2h);
                    hacc += smv[tq * 4 + half * 2 + j] * num * __builtin_amdgcn_rcpf(den);
                }
            }
        }
        hl[wid][bs][lane] = hacc;
    }
    __syncthreads();

    // ---- fc: 4 nodes x 2 batches x 6 t-pairs = 48 threads, packed f2
    if (tid < 48) {
        int nw = tid / 12;
        int rem = tid % 12;
        int bs = rem / 6;
        int tp = rem % 6;
        f2 acc;
        acc[0] = fcb[2 * tp];
        acc[1] = fcb[2 * tp + 1];
        const float* hrow = &hl[nw][bs][0];
#pragma unroll
        for (int o4 = 0; o4 < 16; ++o4) {
            f4v h4 = *(const f4v*)&hrow[o4 * 4];
            f2 w0 = *(const f2*)&fcw[(o4 * 4 + 0) * TT + 2 * tp];
            f2 w1 = *(const f2*)&fcw[(o4 * 4 + 1) * TT + 2 * tp];
            f2 w2 = *(const f2*)&fcw[(o4 * 4 + 2) * TT + 2 * tp];
            f2 w3 = *(const f2*)&fcw[(o4 * 4 + 3) * TT + 2 * tp];
            acc += h4[0] * w0;
            acc += h4[1] * w1;
            acc += h4[2] * w2;
            acc += h4[3] * w3;
        }
        int b = bp + bs * 8;
        int nn2 = g * 4 + nw;
        *(f2*)&out[((size_t)b * NN + nn2) * TT + 2 * tp] = acc;
    }
}

extern "C" void kernel_launch(void* const* d_in, const int* in_sizes, int n_in,
                              void* d_out, int out_size, void* d_ws, size_t ws_size,
                              hipStream_t stream) {
    const float* x   = (const float*)d_in[0];
    const int*   ei  = (const int*)d_in[1];
    const float* Wz  = (const float*)d_in[2];
    const float* bz  = (const float*)d_in[3];
    const float* Lz  = (const float*)d_in[4];
    const float* lbz = (const float*)d_in[5];
    // d_in[6..9] = Wr, br, Lr, lbr : dead (H == 0)
    const float* Wh  = (const float*)d_in[10];
    const float* bh  = (const float*)d_in[11];
    const float* Lh  = (const float*)d_in[12];
    const float* lbh = (const float*)d_in[13];
    const float* att = (const float*)d_in[14];
    const float* fcW = (const float*)d_in[15];
    const float* fcb = (const float*)d_in[16];
    float* out = (float*)d_out;

    const int* src = ei;
    const int* dst = ei + EE;

    int2*  cedge  = (int2*)d_ws;             // CAP entries (zeroed each call)
    int*   deg    = (int*)(cedge + CAP);     // N (zeroed by same memset)
    int*   cursor = deg + NN;                // N
    int*   offs   = cursor + NN;             // N+1
    float* dinv   = (float*)(offs + NN + 1); // N
    float* G      = dinv + NN;               // 2*8*64
    float* C      = G + 1024;                // 2*64
    float* sm     = C + 128;                 // 16

    (void)hipMemsetAsync(d_ws, 0, (size_t)CAP * 8 + (size_t)NN * 4, stream);
    hipLaunchKernelGGL(k_count, dim3((EE + 255) / 256), dim3(256), 0, stream, dst, deg);
    hipLaunchKernelGGL(k_scan_prep, dim3(2), dim3(1024), 0, stream,
                       deg, offs, cursor, dinv,
                       Wz, bz, Lz, lbz, Wh, bh, Lh, lbh, att, G, C, sm);
    hipLaunchKernelGGL(k_fill, dim3((EN + 255) / 256), dim3(256), 0, stream,
                       src, dst, cursor, dinv, cedge);
    hipLaunchKernelGGL(k_fused, dim3(1250 * 8), dim3(256), 0, stream,
                       x, offs, cedge, G, C, sm, fcW, fcb, out);
}